// Round 1
// baseline (5329.144 us; speedup 1.0000x reference)
//
#include <hip/hip_runtime.h>
#include <hip/hip_bf16.h>
#include <math.h>

#define D_MODEL 1024
#define N_HEADS 16
#define HEAD_DIM 64
#define SEQ 2048
#define BATCH 2
#define NEG_BIG 1e10f

// ---------------------------------------------------------------------------
// Baseline fp32 SGEMM: C[M,N] = A[M,K] * B[K,N], all row-major fp32.
// BM=BN=64, BK=16, 256 threads, 4x4 micro-tile per thread.
// All problem dims here are multiples of the tile, so no bounds checks.
// ---------------------------------------------------------------------------
__global__ __launch_bounds__(256) void sgemm_kernel(
    const float* __restrict__ A, const float* __restrict__ B,
    float* __restrict__ C, int M, int N, int Kd) {
  constexpr int BM = 64, BN = 64, BK = 16;
  __shared__ float As[BK][BM];   // transposed A tile for column access
  __shared__ float Bs[BK][BN];

  const int tid = threadIdx.x;
  const int m0 = blockIdx.y * BM;
  const int n0 = blockIdx.x * BN;

  const int ty = tid >> 4;       // 0..15
  const int tx = tid & 15;       // 0..15

  float acc[4][4];
#pragma unroll
  for (int i = 0; i < 4; ++i)
#pragma unroll
    for (int j = 0; j < 4; ++j) acc[i][j] = 0.0f;

  // A-tile load mapping: one float4 per thread (64 rows x 4 float4/row = 256)
  const int a_row = tid >> 2;          // 0..63
  const int a_k4  = (tid & 3) * 4;     // 0,4,8,12
  // B-tile load mapping: one float4 per thread (16 rows x 16 float4/row = 256)
  const int b_row = tid >> 4;          // 0..15
  const int b_n4  = (tid & 15) * 4;    // 0..60

  for (int k0 = 0; k0 < Kd; k0 += BK) {
    // load A tile (transposed into As[k][m])
    const float4 av = *(const float4*)&A[(size_t)(m0 + a_row) * Kd + k0 + a_k4];
    As[a_k4 + 0][a_row] = av.x;
    As[a_k4 + 1][a_row] = av.y;
    As[a_k4 + 2][a_row] = av.z;
    As[a_k4 + 3][a_row] = av.w;
    // load B tile
    *(float4*)&Bs[b_row][b_n4] = *(const float4*)&B[(size_t)(k0 + b_row) * N + n0 + b_n4];
    __syncthreads();

#pragma unroll
    for (int kk = 0; kk < BK; ++kk) {
      float a_reg[4], b_reg[4];
#pragma unroll
      for (int i = 0; i < 4; ++i) a_reg[i] = As[kk][ty * 4 + i];
#pragma unroll
      for (int j = 0; j < 4; ++j) b_reg[j] = Bs[kk][tx * 4 + j];
#pragma unroll
      for (int i = 0; i < 4; ++i)
#pragma unroll
        for (int j = 0; j < 4; ++j) acc[i][j] += a_reg[i] * b_reg[j];
    }
    __syncthreads();
  }

#pragma unroll
  for (int i = 0; i < 4; ++i) {
    float4 cv = make_float4(acc[i][0], acc[i][1], acc[i][2], acc[i][3]);
    *(float4*)&C[(size_t)(m0 + ty * 4 + i) * N + n0 + tx * 4] = cv;
  }
}

// ---------------------------------------------------------------------------
// Flash-style causal attention.
// Grid: (qt=SEQ/64, h=N_HEADS, b=BATCH), block = 256 threads.
// Q/K/V are the full [b, s, d_model] projection outputs; head h lives in
// columns [h*64, h*64+64). Output written head-merged: [b, s, h*64+dh].
// Q-tile = 64 rows, K/V-tile = 32 rows (KT).
// ---------------------------------------------------------------------------
#define QT 64
#define KT 32

__global__ __launch_bounds__(256) void attn_kernel(
    const float* __restrict__ Q, const float* __restrict__ K,
    const float* __restrict__ V, float* __restrict__ O) {
  __shared__ float Qs[QT][HEAD_DIM];   // 16 KB
  __shared__ float Ks[KT][HEAD_DIM];   // 8 KB
  __shared__ float Vs[KT][HEAD_DIM];   // 8 KB
  __shared__ float Ss[QT][KT];         // 8 KB
  __shared__ float m_sh[QT], l_sh[QT], alpha_sh[QT];

  const int tid = threadIdx.x;
  const int qt = blockIdx.x;
  const int h  = blockIdx.y;
  const int b  = blockIdx.z;
  const int qr0 = qt * QT;
  const size_t base = ((size_t)b * SEQ) * D_MODEL + h * HEAD_DIM;
  const float scale = 0.03125f;  // 1/sqrt(1024)

  // Load Q tile: 64 rows x 16 float4
  for (int i = tid; i < QT * (HEAD_DIM / 4); i += 256) {
    const int r = i >> 4, c4 = (i & 15) * 4;
    *(float4*)&Qs[r][c4] = *(const float4*)&Q[base + (size_t)(qr0 + r) * D_MODEL + c4];
  }
  if (tid < QT) {
    m_sh[tid] = -INFINITY;
    l_sh[tid] = 0.0f;
  }

  // Per-thread ownership: row r = tid>>2 (shared by 4 threads),
  //  S columns  cs..cs+7   (cs = (tid&3)*8)
  //  O dh-cols  os..os+15  (os = (tid&3)*16)
  const int r  = tid >> 2;
  const int cs = (tid & 3) * 8;
  const int os = (tid & 3) * 16;
  float o_acc[16];
#pragma unroll
  for (int j = 0; j < 16; ++j) o_acc[j] = 0.0f;

  const int kt_max = 2 * qt + 1;  // causal: k rows up to qr0+63
  for (int kt = 0; kt <= kt_max; ++kt) {
    const int kr0 = kt * KT;
    __syncthreads();
    // load K/V tiles: 32 rows x 16 float4 = 512 float4
    for (int i = tid; i < KT * (HEAD_DIM / 4); i += 256) {
      const int rr = i >> 4, c4 = (i & 15) * 4;
      *(float4*)&Ks[rr][c4] = *(const float4*)&K[base + (size_t)(kr0 + rr) * D_MODEL + c4];
      *(float4*)&Vs[rr][c4] = *(const float4*)&V[base + (size_t)(kr0 + rr) * D_MODEL + c4];
    }
    __syncthreads();

    // S[r][c] = (Q[r]·K[c]) * scale  (masked: -NEG_BIG)
#pragma unroll
    for (int cc = 0; cc < 8; ++cc) {
      const int c = cs + cc;
      float dot = 0.0f;
#pragma unroll
      for (int d = 0; d < HEAD_DIM; ++d) dot += Qs[r][d] * Ks[c][d];
      float s = dot * scale;
      if (kr0 + c > qr0 + r) s -= NEG_BIG;
      Ss[r][c] = s;
    }
    __syncthreads();

    // online softmax per row (64 threads, one per row)
    if (tid < QT) {
      float tmax = Ss[tid][0];
      for (int c = 1; c < KT; ++c) tmax = fmaxf(tmax, Ss[tid][c]);
      const float m_old = m_sh[tid];
      const float m_new = fmaxf(m_old, tmax);
      const float alpha = __expf(m_old - m_new);
      float psum = 0.0f;
      for (int c = 0; c < KT; ++c) {
        const float p = __expf(Ss[tid][c] - m_new);
        Ss[tid][c] = p;
        psum += p;
      }
      m_sh[tid] = m_new;
      l_sh[tid] = l_sh[tid] * alpha + psum;
      alpha_sh[tid] = alpha;
    }
    __syncthreads();

    // O = O*alpha + P @ V
    const float a = alpha_sh[r];
#pragma unroll
    for (int j = 0; j < 16; ++j) o_acc[j] *= a;
    for (int c = 0; c < KT; ++c) {
      const float p = Ss[r][c];
#pragma unroll
      for (int j = 0; j < 16; ++j) o_acc[j] += p * Vs[c][os + j];
    }
  }

  // epilogue: divide by l, write head-merged
  const float inv_l = 1.0f / l_sh[r];
  float4 v0 = make_float4(o_acc[0] * inv_l, o_acc[1] * inv_l, o_acc[2] * inv_l, o_acc[3] * inv_l);
  float4 v1 = make_float4(o_acc[4] * inv_l, o_acc[5] * inv_l, o_acc[6] * inv_l, o_acc[7] * inv_l);
  float4 v2 = make_float4(o_acc[8] * inv_l, o_acc[9] * inv_l, o_acc[10] * inv_l, o_acc[11] * inv_l);
  float4 v3 = make_float4(o_acc[12] * inv_l, o_acc[13] * inv_l, o_acc[14] * inv_l, o_acc[15] * inv_l);
  float* dst = &O[base + (size_t)(qr0 + r) * D_MODEL + os];
  *(float4*)&dst[0]  = v0;
  *(float4*)&dst[4]  = v1;
  *(float4*)&dst[8]  = v2;
  *(float4*)&dst[12] = v3;
}

// ---------------------------------------------------------------------------
extern "C" void kernel_launch(void* const* d_in, const int* in_sizes, int n_in,
                              void* d_out, int out_size, void* d_ws, size_t ws_size,
                              hipStream_t stream) {
  const float* x  = (const float*)d_in[0];
  const float* qw = (const float*)d_in[1];
  const float* kw = (const float*)d_in[2];
  const float* vw = (const float*)d_in[3];
  const float* ow = (const float*)d_in[4];
  float* out = (float*)d_out;

  const int M = BATCH * SEQ;          // 4096
  const size_t mat = (size_t)M * D_MODEL;  // 4M floats = 16 MB

  float* Q    = (float*)d_ws;
  float* Kbuf = Q + mat;
  float* Vbuf = Kbuf + mat;
  float* attn = Vbuf + mat;           // total 64 MB of d_ws

  dim3 gblock(256);
  dim3 ggrid(D_MODEL / 64, M / 64);   // (16, 64)

  sgemm_kernel<<<ggrid, gblock, 0, stream>>>(x, qw, Q,    M, D_MODEL, D_MODEL);
  sgemm_kernel<<<ggrid, gblock, 0, stream>>>(x, kw, Kbuf, M, D_MODEL, D_MODEL);
  sgemm_kernel<<<ggrid, gblock, 0, stream>>>(x, vw, Vbuf, M, D_MODEL, D_MODEL);

  dim3 agrid(SEQ / QT, N_HEADS, BATCH);  // (32, 16, 2)
  attn_kernel<<<agrid, 256, 0, stream>>>(Q, Kbuf, Vbuf, attn);

  sgemm_kernel<<<ggrid, gblock, 0, stream>>>(attn, ow, out, M, D_MODEL, D_MODEL);
}

// Round 3
// 744.343 us; speedup vs baseline: 7.1595x; 7.1595x over previous
//
#include <hip/hip_runtime.h>
#include <hip/hip_bf16.h>
#include <math.h>

#define D_MODEL 1024
#define N_HEADS 16
#define HEAD_DIM 64
#define SEQ 2048
#define BATCH 2

typedef __attribute__((ext_vector_type(8))) short short8;
typedef __attribute__((ext_vector_type(4))) float f32x4;

__device__ __forceinline__ unsigned short f2bf(float x) {
  union { float f; unsigned u; } v; v.f = x;
  unsigned r = v.u + 0x7FFFu + ((v.u >> 16) & 1u);
  return (unsigned short)(r >> 16);
}
__device__ __forceinline__ float bf2f(unsigned short h) {
  return __uint_as_float((unsigned)h << 16);
}

// ---------------------------------------------------------------------------
// fp32 SGEMM: C[M,N] = A[M,K]*B[K,N].
// MODE 0: fp32 C.  MODE 1: bf16 hi/lo pair (Chi = bf16(C), Clo = bf16(C-Chi)).
// BM=BN=64, BK=16, 256 threads, 4x4 micro-tile.
// ---------------------------------------------------------------------------
template <int MODE>
__global__ __launch_bounds__(256) void sgemm_kernel(
    const float* __restrict__ A, const float* __restrict__ B,
    float* __restrict__ C, unsigned short* __restrict__ Chi,
    unsigned short* __restrict__ Clo, int M, int N, int Kd) {
  constexpr int BM = 64, BN = 64, BK = 16;
  __shared__ float As[BK][BM];
  __shared__ float Bs[BK][BN];

  const int tid = threadIdx.x;
  const int m0 = blockIdx.y * BM;
  const int n0 = blockIdx.x * BN;
  const int ty = tid >> 4;
  const int tx = tid & 15;

  float acc[4][4];
#pragma unroll
  for (int i = 0; i < 4; ++i)
#pragma unroll
    for (int j = 0; j < 4; ++j) acc[i][j] = 0.0f;

  const int a_row = tid >> 2;
  const int a_k4  = (tid & 3) * 4;
  const int b_row = tid >> 4;
  const int b_n4  = (tid & 15) * 4;

  for (int k0 = 0; k0 < Kd; k0 += BK) {
    const float4 av = *(const float4*)&A[(size_t)(m0 + a_row) * Kd + k0 + a_k4];
    As[a_k4 + 0][a_row] = av.x;
    As[a_k4 + 1][a_row] = av.y;
    As[a_k4 + 2][a_row] = av.z;
    As[a_k4 + 3][a_row] = av.w;
    *(float4*)&Bs[b_row][b_n4] = *(const float4*)&B[(size_t)(k0 + b_row) * N + n0 + b_n4];
    __syncthreads();

#pragma unroll
    for (int kk = 0; kk < BK; ++kk) {
      float a_reg[4], b_reg[4];
#pragma unroll
      for (int i = 0; i < 4; ++i) a_reg[i] = As[kk][ty * 4 + i];
#pragma unroll
      for (int j = 0; j < 4; ++j) b_reg[j] = Bs[kk][tx * 4 + j];
#pragma unroll
      for (int i = 0; i < 4; ++i)
#pragma unroll
        for (int j = 0; j < 4; ++j) acc[i][j] += a_reg[i] * b_reg[j];
    }
    __syncthreads();
  }

#pragma unroll
  for (int i = 0; i < 4; ++i) {
    const size_t off = (size_t)(m0 + ty * 4 + i) * N + n0 + tx * 4;
    if constexpr (MODE == 0) {
      *(float4*)&C[off] = make_float4(acc[i][0], acc[i][1], acc[i][2], acc[i][3]);
    } else {
      unsigned short h[4], l[4];
#pragma unroll
      for (int j = 0; j < 4; ++j) {
        h[j] = f2bf(acc[i][j]);
        l[j] = f2bf(acc[i][j] - bf2f(h[j]));
      }
      uint2 ph, pl;
      ph.x = (unsigned)h[0] | ((unsigned)h[1] << 16);
      ph.y = (unsigned)h[2] | ((unsigned)h[3] << 16);
      pl.x = (unsigned)l[0] | ((unsigned)l[1] << 16);
      pl.y = (unsigned)l[2] | ((unsigned)l[3] << 16);
      *(uint2*)&Chi[off] = ph;
      *(uint2*)&Clo[off] = pl;
    }
  }
}

// ---------------------------------------------------------------------------
// V fp32 [B*S][D_MODEL] -> Vt bf16 [B][H][HEAD_DIM][S]  (tiled transpose)
// ---------------------------------------------------------------------------
__global__ __launch_bounds__(256) void transpose_v_kernel(
    const float* __restrict__ V, unsigned short* __restrict__ Vt) {
  __shared__ float t[32][33];
  const int s0 = blockIdx.x * 32;
  const int d0 = blockIdx.y * 32;
  const int b  = blockIdx.z;
  const int tx = threadIdx.x & 31;
  const int ty = threadIdx.x >> 5;

#pragma unroll
  for (int i = 0; i < 32; i += 8)
    t[ty + i][tx] = V[((size_t)b * SEQ + s0 + ty + i) * D_MODEL + d0 + tx];
  __syncthreads();
#pragma unroll
  for (int i = 0; i < 32; i += 8) {
    const int d = d0 + ty + i;
    Vt[(((size_t)b * N_HEADS + (d >> 6)) * HEAD_DIM + (d & 63)) * SEQ + s0 + tx] =
        f2bf(t[tx][ty + i]);
  }
}

// ---------------------------------------------------------------------------
// MFMA flash attention (causal), hi/lo-split QK^T for ~fp32 score precision.
// grid (SEQ/64, N_HEADS, BATCH), block 256 = 4 waves; wave w owns q rows
// [qr0+16w, qr0+16w+16). S^T = Khi·Qhi^T + Khi·Qlo^T + Klo·Qhi^T,
// online softmax per-lane, O^T = V^T·P^T. All 16x16x32 bf16 MFMA.
// ---------------------------------------------------------------------------
#define PSTR 72  // LDS row stride in bf16 (64 data + 8 pad)

__global__ __launch_bounds__(256) void attn_mfma_kernel(
    const unsigned short* __restrict__ Qhi, const unsigned short* __restrict__ Qlo,
    const unsigned short* __restrict__ Khi, const unsigned short* __restrict__ Klo,
    const unsigned short* __restrict__ Vt,  // bf16 [B][H][HEAD_DIM][S]
    float* __restrict__ O) {                // fp32 [B*S][D_MODEL] head-merged
  __shared__ __align__(16) unsigned short Khs[64 * PSTR];
  __shared__ __align__(16) unsigned short Kls[64 * PSTR];
  __shared__ __align__(16) unsigned short Vs[64 * PSTR];
  __shared__ __align__(16) unsigned short Ps[64 * PSTR];

  const int tid = threadIdx.x;
  const int lane = tid & 63;
  const int w = tid >> 6;
  const int lq = lane & 15;
  const int g = lane >> 4;
  const int q_blk = w * 16 + lq;
  const int qt = blockIdx.x;
  const int h = blockIdx.y;
  const int b = blockIdx.z;
  const int qr0 = qt * 64;

  const size_t qk_base = ((size_t)b * SEQ) * D_MODEL + (size_t)h * HEAD_DIM;
  const unsigned short* Vtb = Vt + ((size_t)(b * N_HEADS + h) * HEAD_DIM) * SEQ;

  // Q B-fragments straight from global: B[k=d][n=q], lane reads 8 contiguous d
  const size_t qoff = qk_base + (size_t)(qr0 + q_blk) * D_MODEL;
  const short8 qh0 = *(const short8*)&Qhi[qoff + g * 8];
  const short8 qh1 = *(const short8*)&Qhi[qoff + g * 8 + 32];
  const short8 ql0 = *(const short8*)&Qlo[qoff + g * 8];
  const short8 ql1 = *(const short8*)&Qlo[qoff + g * 8 + 32];

  f32x4 Ot[4];
#pragma unroll
  for (int mt = 0; mt < 4; ++mt) Ot[mt] = (f32x4){0.f, 0.f, 0.f, 0.f};
  float m_run = -INFINITY, l_run = 0.f;
  const float scale = 0.03125f;  // 1/sqrt(1024)

  for (int kt = 0; kt <= qt; ++kt) {
    const int kr0 = kt * 64;
    __syncthreads();
#pragma unroll
    for (int it = 0; it < 2; ++it) {
      const int id = it * 256 + tid;
      const int r = id >> 3, c8 = (id & 7) * 8;
      const size_t koff = qk_base + (size_t)(kr0 + r) * D_MODEL + c8;
      *(uint4*)&Khs[r * PSTR + c8] = *(const uint4*)&Khi[koff];
      *(uint4*)&Kls[r * PSTR + c8] = *(const uint4*)&Klo[koff];
      *(uint4*)&Vs[r * PSTR + c8]  = *(const uint4*)&Vtb[(size_t)r * SEQ + kr0 + c8];
    }
    __syncthreads();

    // S^T[k][q]: 4 k-subtiles x 6 MFMAs (hi·hi, hi·lo, lo·hi over two d-halves)
    f32x4 S[4];
#pragma unroll
    for (int st = 0; st < 4; ++st) {
      const unsigned short* khr = &Khs[(st * 16 + lq) * PSTR];
      const unsigned short* klr = &Kls[(st * 16 + lq) * PSTR];
      const short8 kh0 = *(const short8*)&khr[g * 8];
      const short8 kh1 = *(const short8*)&khr[g * 8 + 32];
      const short8 kl0 = *(const short8*)&klr[g * 8];
      const short8 kl1 = *(const short8*)&klr[g * 8 + 32];
      f32x4 s = (f32x4){0.f, 0.f, 0.f, 0.f};
      s = __builtin_amdgcn_mfma_f32_16x16x32_bf16(kh0, qh0, s, 0, 0, 0);
      s = __builtin_amdgcn_mfma_f32_16x16x32_bf16(kh1, qh1, s, 0, 0, 0);
      s = __builtin_amdgcn_mfma_f32_16x16x32_bf16(kh0, ql0, s, 0, 0, 0);
      s = __builtin_amdgcn_mfma_f32_16x16x32_bf16(kh1, ql1, s, 0, 0, 0);
      s = __builtin_amdgcn_mfma_f32_16x16x32_bf16(kl0, qh0, s, 0, 0, 0);
      s = __builtin_amdgcn_mfma_f32_16x16x32_bf16(kl1, qh1, s, 0, 0, 0);
      S[st] = s;
    }

    // online softmax: lane owns q-column q_blk; S^T rows k = st*16 + g*4 + r
    const bool diag = (kt == qt);
    float sv[16];
    float tmax = -INFINITY;
#pragma unroll
    for (int st = 0; st < 4; ++st)
#pragma unroll
      for (int r = 0; r < 4; ++r) {
        float s = S[st][r] * scale;
        if (diag && (st * 16 + g * 4 + r) > q_blk) s = -1e30f;
        sv[st * 4 + r] = s;
        tmax = fmaxf(tmax, s);
      }
    tmax = fmaxf(tmax, __shfl_xor(tmax, 16));
    tmax = fmaxf(tmax, __shfl_xor(tmax, 32));
    const float m_new = fmaxf(m_run, tmax);
    const float alpha = __expf(m_run - m_new);
    m_run = m_new;
    float psum = 0.f;
#pragma unroll
    for (int i = 0; i < 16; ++i) {
      sv[i] = __expf(sv[i] - m_new);
      psum += sv[i];
    }
    psum += __shfl_xor(psum, 16);
    psum += __shfl_xor(psum, 32);
    l_run = l_run * alpha + psum;
#pragma unroll
    for (int mt = 0; mt < 4; ++mt) {
      Ot[mt][0] *= alpha; Ot[mt][1] *= alpha;
      Ot[mt][2] *= alpha; Ot[mt][3] *= alpha;
    }

    // P^T (C-layout) -> LDS as P[q][k]; wave-private rows
#pragma unroll
    for (int st = 0; st < 4; ++st) {
      uint2 pk;
      pk.x = (unsigned)f2bf(sv[st * 4 + 0]) | ((unsigned)f2bf(sv[st * 4 + 1]) << 16);
      pk.y = (unsigned)f2bf(sv[st * 4 + 2]) | ((unsigned)f2bf(sv[st * 4 + 3]) << 16);
      *(uint2*)&Ps[q_blk * PSTR + st * 16 + g * 4] = pk;
    }
    const short8 pf0 = *(const short8*)&Ps[q_blk * PSTR + g * 8];
    const short8 pf1 = *(const short8*)&Ps[q_blk * PSTR + g * 8 + 32];

    // O^T = V^T·P^T : 4 dh-subtiles x 2 MFMAs over k
#pragma unroll
    for (int mt = 0; mt < 4; ++mt) {
      const unsigned short* vrow = &Vs[(mt * 16 + lq) * PSTR];
      const short8 vf0 = *(const short8*)&vrow[g * 8];
      const short8 vf1 = *(const short8*)&vrow[g * 8 + 32];
      Ot[mt] = __builtin_amdgcn_mfma_f32_16x16x32_bf16(vf0, pf0, Ot[mt], 0, 0, 0);
      Ot[mt] = __builtin_amdgcn_mfma_f32_16x16x32_bf16(vf1, pf1, Ot[mt], 0, 0, 0);
    }
  }

  // epilogue: lane holds O[q=qr0+q_blk][dh = mt*16 + g*4 + r]
  const float inv_l = 1.0f / l_run;
  float* orow = &O[qk_base + (size_t)(qr0 + q_blk) * D_MODEL];
#pragma unroll
  for (int mt = 0; mt < 4; ++mt) {
    float4 ov;
    ov.x = Ot[mt][0] * inv_l;
    ov.y = Ot[mt][1] * inv_l;
    ov.z = Ot[mt][2] * inv_l;
    ov.w = Ot[mt][3] * inv_l;
    *(float4*)&orow[mt * 16 + g * 4] = ov;
  }
}

// ---------------------------------------------------------------------------
extern "C" void kernel_launch(void* const* d_in, const int* in_sizes, int n_in,
                              void* d_out, int out_size, void* d_ws, size_t ws_size,
                              hipStream_t stream) {
  const float* x  = (const float*)d_in[0];
  const float* qw = (const float*)d_in[1];
  const float* kw = (const float*)d_in[2];
  const float* vw = (const float*)d_in[3];
  const float* ow = (const float*)d_in[4];
  float* out = (float*)d_out;

  const int M = BATCH * SEQ;               // 4096
  const size_t mat = (size_t)M * D_MODEL;  // 4M elements

  // ws layout (56 MB): Qhi,Qlo,Khi,Klo,Vt bf16 (5 x 8 MB) + Vf/At fp32 (16 MB)
  unsigned short* Qhi = (unsigned short*)d_ws;
  unsigned short* Qlo = Qhi + mat;
  unsigned short* Khi = Qlo + mat;
  unsigned short* Klo = Khi + mat;
  unsigned short* Vt  = Klo + mat;
  float*          Vf  = (float*)(Vt + mat);
  float*          At  = Vf;  // alias: Vf dead after transpose

  dim3 gblock(256);
  dim3 ggrid(D_MODEL / 64, M / 64);  // (16, 64)

  sgemm_kernel<1><<<ggrid, gblock, 0, stream>>>(x, qw, nullptr, Qhi, Qlo, M, D_MODEL, D_MODEL);
  sgemm_kernel<1><<<ggrid, gblock, 0, stream>>>(x, kw, nullptr, Khi, Klo, M, D_MODEL, D_MODEL);
  sgemm_kernel<0><<<ggrid, gblock, 0, stream>>>(x, vw, Vf, nullptr, nullptr, M, D_MODEL, D_MODEL);

  transpose_v_kernel<<<dim3(SEQ / 32, D_MODEL / 32, BATCH), 256, 0, stream>>>(Vf, Vt);

  attn_mfma_kernel<<<dim3(SEQ / 64, N_HEADS, BATCH), 256, 0, stream>>>(
      Qhi, Qlo, Khi, Klo, Vt, At);

  sgemm_kernel<0><<<ggrid, gblock, 0, stream>>>(At, ow, out, nullptr, nullptr, M, D_MODEL, D_MODEL);
}

// Round 4
// 432.576 us; speedup vs baseline: 12.3196x; 1.7207x over previous
//
#include <hip/hip_runtime.h>
#include <hip/hip_bf16.h>
#include <math.h>

#define D_MODEL 1024
#define N_HEADS 16
#define HEAD_DIM 64
#define SEQ 2048
#define BATCH 2

typedef __attribute__((ext_vector_type(8))) short short8;
typedef __attribute__((ext_vector_type(4))) float f32x4;

__device__ __forceinline__ unsigned short f2bf(float x) {
  union { float f; unsigned u; } v; v.f = x;
  unsigned r = v.u + 0x7FFFu + ((v.u >> 16) & 1u);
  return (unsigned short)(r >> 16);
}
__device__ __forceinline__ float bf2f(unsigned short h) {
  return __uint_as_float((unsigned)h << 16);
}
// Truncation hi/lo split: hi = trunc-to-bf16(x), lo = rne-bf16(x - hi).
// Pair represents x to ~2^-17 relative; cheaper than double-RNE.
__device__ __forceinline__ void split2(float x, unsigned short& h, unsigned short& l) {
  union { float f; unsigned u; } v; v.f = x;
  h = (unsigned short)(v.u >> 16);
  l = f2bf(x - __uint_as_float(v.u & 0xFFFF0000u));
}
__device__ __forceinline__ void glds16(const unsigned short* g, unsigned short* l) {
  __builtin_amdgcn_global_load_lds(
      (const __attribute__((address_space(1))) void*)g,
      (__attribute__((address_space(3))) void*)l, 16, 0, 0);
}

// ---------------------------------------------------------------------------
// Weight transpose + bf16 split: W fp32 [K][N] -> Thi/Tlo bf16 [N][K].
// ---------------------------------------------------------------------------
template <bool LO>
__global__ __launch_bounds__(256) void wsplit_kernel(
    const float* __restrict__ W, unsigned short* __restrict__ Thi,
    unsigned short* __restrict__ Tlo) {
  __shared__ float t[32][33];
  const int k0 = blockIdx.x * 32, n0 = blockIdx.y * 32;
  const int tx = threadIdx.x & 31, ty = threadIdx.x >> 5;
#pragma unroll
  for (int i = 0; i < 32; i += 8)
    t[ty + i][tx] = W[(size_t)(k0 + ty + i) * D_MODEL + n0 + tx];
  __syncthreads();
#pragma unroll
  for (int i = 0; i < 32; i += 8) {
    unsigned short h, l;
    split2(t[tx][ty + i], h, l);
    const size_t off = (size_t)(n0 + ty + i) * D_MODEL + k0 + tx;
    Thi[off] = h;
    if (LO) Tlo[off] = l;
  }
}

// ---------------------------------------------------------------------------
// Single-wave MFMA GEMM: C[M,N] = A[M,K] * B^T[N,K]^T, 64x64 tile per block,
// 64 threads (1 wave), BK=32, 16x16x32 bf16 MFMA.
// AMODE 0: A fp32 -> bf16 staged. 1: A fp32 -> hi/lo staged, B hi/lo (3-MFMA
// precision recovery). 2: A already bf16 (global_load_lds direct).
// CMODE 0: fp32 C row-major. 1: bf16 hi/lo C pair. 2: bf16 C transposed into
// Vt[b][h][dh][s] layout.
// ---------------------------------------------------------------------------
template <int AMODE, int CMODE>
__global__ __launch_bounds__(64) void gemm64_kernel(
    const void* __restrict__ Asrc, const unsigned short* __restrict__ Bhig,
    const unsigned short* __restrict__ Blog, void* __restrict__ C0,
    unsigned short* __restrict__ C1) {
  constexpr bool HILO = (AMODE == 1);
  constexpr int K = D_MODEL;
  __shared__ __align__(16) unsigned short Ah[64 * 32];
  __shared__ __align__(16) unsigned short Bh[64 * 32];
  __shared__ __align__(16) unsigned short Al[HILO ? 64 * 32 : 8];
  __shared__ __align__(16) unsigned short Bl[HILO ? 64 * 32 : 8];

  const int tid = threadIdx.x;  // 0..63, single wave
  const int lq = tid & 15, g = tid >> 4;
  const int n0 = blockIdx.x * 64;
  const int m0 = blockIdx.y * 64;

  f32x4 acc[4][4];
#pragma unroll
  for (int mi = 0; mi < 4; ++mi)
#pragma unroll
    for (int ni = 0; ni < 4; ++ni) acc[mi][ni] = (f32x4){0.f, 0.f, 0.f, 0.f};

  for (int k0 = 0; k0 < K; k0 += 32) {
    __syncthreads();  // protect LDS from previous iteration's reads
#pragma unroll
    for (int it = 0; it < 4; ++it) {
      const int e = it * 64 + tid;
      const int r = e >> 2, c8 = (e & 3) * 8;
      glds16(&Bhig[(size_t)(n0 + r) * K + k0 + c8], &Bh[e * 8]);
      if constexpr (HILO) glds16(&Blog[(size_t)(n0 + r) * K + k0 + c8], &Bl[e * 8]);
      if constexpr (AMODE == 2)
        glds16(&((const unsigned short*)Asrc)[(size_t)(m0 + r) * K + k0 + c8],
               &Ah[e * 8]);
    }
    if constexpr (AMODE != 2) {
      const float* Af = (const float*)Asrc;
#pragma unroll
      for (int j = 0; j < 8; ++j) {
        const int e = j * 64 + tid;
        const int r = e >> 3, c4 = (e & 7) * 4;
        const float4 v = *(const float4*)&Af[(size_t)(m0 + r) * K + k0 + c4];
        if constexpr (HILO) {
          unsigned short h0, h1, h2, h3, l0, l1, l2, l3;
          split2(v.x, h0, l0); split2(v.y, h1, l1);
          split2(v.z, h2, l2); split2(v.w, h3, l3);
          uint2 ph, pl;
          ph.x = (unsigned)h0 | ((unsigned)h1 << 16);
          ph.y = (unsigned)h2 | ((unsigned)h3 << 16);
          pl.x = (unsigned)l0 | ((unsigned)l1 << 16);
          pl.y = (unsigned)l2 | ((unsigned)l3 << 16);
          *(uint2*)&Ah[r * 32 + c4] = ph;
          *(uint2*)&Al[r * 32 + c4] = pl;
        } else {
          uint2 ph;
          ph.x = (unsigned)f2bf(v.x) | ((unsigned)f2bf(v.y) << 16);
          ph.y = (unsigned)f2bf(v.z) | ((unsigned)f2bf(v.w) << 16);
          *(uint2*)&Ah[r * 32 + c4] = ph;
        }
      }
    }
    __syncthreads();  // drains global_load_lds (vmcnt) + ds_writes

    short8 ah[4], bh[4], al[4], bl[4];
#pragma unroll
    for (int i = 0; i < 4; ++i) {
      ah[i] = *(const short8*)&Ah[(i * 16 + lq) * 32 + g * 8];
      bh[i] = *(const short8*)&Bh[(i * 16 + lq) * 32 + g * 8];
      if constexpr (HILO) {
        al[i] = *(const short8*)&Al[(i * 16 + lq) * 32 + g * 8];
        bl[i] = *(const short8*)&Bl[(i * 16 + lq) * 32 + g * 8];
      }
    }
#pragma unroll
    for (int mi = 0; mi < 4; ++mi)
#pragma unroll
      for (int ni = 0; ni < 4; ++ni) {
        acc[mi][ni] = __builtin_amdgcn_mfma_f32_16x16x32_bf16(ah[mi], bh[ni], acc[mi][ni], 0, 0, 0);
        if constexpr (HILO) {
          acc[mi][ni] = __builtin_amdgcn_mfma_f32_16x16x32_bf16(ah[mi], bl[ni], acc[mi][ni], 0, 0, 0);
          acc[mi][ni] = __builtin_amdgcn_mfma_f32_16x16x32_bf16(al[mi], bh[ni], acc[mi][ni], 0, 0, 0);
        }
      }
  }

  // Epilogue: lane holds C[gm + r][gn], r=0..3 (C-layout: col=lq, row=g*4+r)
#pragma unroll
  for (int mi = 0; mi < 4; ++mi)
#pragma unroll
    for (int ni = 0; ni < 4; ++ni) {
      const int gm = m0 + mi * 16 + g * 4;
      const int gn = n0 + ni * 16 + lq;
      if constexpr (CMODE == 0) {
        float* C = (float*)C0;
#pragma unroll
        for (int r = 0; r < 4; ++r)
          C[(size_t)(gm + r) * D_MODEL + gn] = acc[mi][ni][r];
      } else if constexpr (CMODE == 1) {
        unsigned short* Chi = (unsigned short*)C0;
#pragma unroll
        for (int r = 0; r < 4; ++r) {
          unsigned short h, l;
          split2(acc[mi][ni][r], h, l);
          Chi[(size_t)(gm + r) * D_MODEL + gn] = h;
          C1[(size_t)(gm + r) * D_MODEL + gn] = l;
        }
      } else {  // CMODE 2: Vt[b][h][dh][s], rows gm are 4 consecutive s
        const int bb = gm >> 11, s = gm & 2047;
        const int hh = gn >> 6, dh = gn & 63;
        uint2 pk;
        pk.x = (unsigned)f2bf(acc[mi][ni][0]) | ((unsigned)f2bf(acc[mi][ni][1]) << 16);
        pk.y = (unsigned)f2bf(acc[mi][ni][2]) | ((unsigned)f2bf(acc[mi][ni][3]) << 16);
        unsigned short* Vt = (unsigned short*)C0;
        *(uint2*)&Vt[(((size_t)bb * N_HEADS + hh) * HEAD_DIM + dh) * SEQ + s] = pk;
      }
    }
}

// ---------------------------------------------------------------------------
// MFMA flash attention (causal), hi/lo-split QK^T. Unchanged from round 3
// except the output is now bf16 (feeds the bf16 out-projection GEMM).
// ---------------------------------------------------------------------------
#define PSTR 72  // LDS row stride in bf16 (64 data + 8 pad)

__global__ __launch_bounds__(256) void attn_mfma_kernel(
    const unsigned short* __restrict__ Qhi, const unsigned short* __restrict__ Qlo,
    const unsigned short* __restrict__ Khi, const unsigned short* __restrict__ Klo,
    const unsigned short* __restrict__ Vt,  // bf16 [B][H][HEAD_DIM][S]
    unsigned short* __restrict__ O) {       // bf16 [B*S][D_MODEL] head-merged
  __shared__ __align__(16) unsigned short Khs[64 * PSTR];
  __shared__ __align__(16) unsigned short Kls[64 * PSTR];
  __shared__ __align__(16) unsigned short Vs[64 * PSTR];
  __shared__ __align__(16) unsigned short Ps[64 * PSTR];

  const int tid = threadIdx.x;
  const int lane = tid & 63;
  const int w = tid >> 6;
  const int lq = lane & 15;
  const int g = lane >> 4;
  const int q_blk = w * 16 + lq;
  const int qt = blockIdx.x;
  const int h = blockIdx.y;
  const int b = blockIdx.z;
  const int qr0 = qt * 64;

  const size_t qk_base = ((size_t)b * SEQ) * D_MODEL + (size_t)h * HEAD_DIM;
  const unsigned short* Vtb = Vt + ((size_t)(b * N_HEADS + h) * HEAD_DIM) * SEQ;

  const size_t qoff = qk_base + (size_t)(qr0 + q_blk) * D_MODEL;
  const short8 qh0 = *(const short8*)&Qhi[qoff + g * 8];
  const short8 qh1 = *(const short8*)&Qhi[qoff + g * 8 + 32];
  const short8 ql0 = *(const short8*)&Qlo[qoff + g * 8];
  const short8 ql1 = *(const short8*)&Qlo[qoff + g * 8 + 32];

  f32x4 Ot[4];
#pragma unroll
  for (int mt = 0; mt < 4; ++mt) Ot[mt] = (f32x4){0.f, 0.f, 0.f, 0.f};
  float m_run = -INFINITY, l_run = 0.f;
  const float scale = 0.03125f;  // 1/sqrt(1024)

  for (int kt = 0; kt <= qt; ++kt) {
    const int kr0 = kt * 64;
    __syncthreads();
#pragma unroll
    for (int it = 0; it < 2; ++it) {
      const int id = it * 256 + tid;
      const int r = id >> 3, c8 = (id & 7) * 8;
      const size_t koff = qk_base + (size_t)(kr0 + r) * D_MODEL + c8;
      *(uint4*)&Khs[r * PSTR + c8] = *(const uint4*)&Khi[koff];
      *(uint4*)&Kls[r * PSTR + c8] = *(const uint4*)&Klo[koff];
      *(uint4*)&Vs[r * PSTR + c8]  = *(const uint4*)&Vtb[(size_t)r * SEQ + kr0 + c8];
    }
    __syncthreads();

    f32x4 S[4];
#pragma unroll
    for (int st = 0; st < 4; ++st) {
      const unsigned short* khr = &Khs[(st * 16 + lq) * PSTR];
      const unsigned short* klr = &Kls[(st * 16 + lq) * PSTR];
      const short8 kh0 = *(const short8*)&khr[g * 8];
      const short8 kh1 = *(const short8*)&khr[g * 8 + 32];
      const short8 kl0 = *(const short8*)&klr[g * 8];
      const short8 kl1 = *(const short8*)&klr[g * 8 + 32];
      f32x4 s = (f32x4){0.f, 0.f, 0.f, 0.f};
      s = __builtin_amdgcn_mfma_f32_16x16x32_bf16(kh0, qh0, s, 0, 0, 0);
      s = __builtin_amdgcn_mfma_f32_16x16x32_bf16(kh1, qh1, s, 0, 0, 0);
      s = __builtin_amdgcn_mfma_f32_16x16x32_bf16(kh0, ql0, s, 0, 0, 0);
      s = __builtin_amdgcn_mfma_f32_16x16x32_bf16(kh1, ql1, s, 0, 0, 0);
      s = __builtin_amdgcn_mfma_f32_16x16x32_bf16(kl0, qh0, s, 0, 0, 0);
      s = __builtin_amdgcn_mfma_f32_16x16x32_bf16(kl1, qh1, s, 0, 0, 0);
      S[st] = s;
    }

    const bool diag = (kt == qt);
    float sv[16];
    float tmax = -INFINITY;
#pragma unroll
    for (int st = 0; st < 4; ++st)
#pragma unroll
      for (int r = 0; r < 4; ++r) {
        float s = S[st][r] * scale;
        if (diag && (st * 16 + g * 4 + r) > q_blk) s = -1e30f;
        sv[st * 4 + r] = s;
        tmax = fmaxf(tmax, s);
      }
    tmax = fmaxf(tmax, __shfl_xor(tmax, 16));
    tmax = fmaxf(tmax, __shfl_xor(tmax, 32));
    const float m_new = fmaxf(m_run, tmax);
    const float alpha = __expf(m_run - m_new);
    m_run = m_new;
    float psum = 0.f;
#pragma unroll
    for (int i = 0; i < 16; ++i) {
      sv[i] = __expf(sv[i] - m_new);
      psum += sv[i];
    }
    psum += __shfl_xor(psum, 16);
    psum += __shfl_xor(psum, 32);
    l_run = l_run * alpha + psum;
#pragma unroll
    for (int mt = 0; mt < 4; ++mt) {
      Ot[mt][0] *= alpha; Ot[mt][1] *= alpha;
      Ot[mt][2] *= alpha; Ot[mt][3] *= alpha;
    }

#pragma unroll
    for (int st = 0; st < 4; ++st) {
      uint2 pk;
      pk.x = (unsigned)f2bf(sv[st * 4 + 0]) | ((unsigned)f2bf(sv[st * 4 + 1]) << 16);
      pk.y = (unsigned)f2bf(sv[st * 4 + 2]) | ((unsigned)f2bf(sv[st * 4 + 3]) << 16);
      *(uint2*)&Ps[q_blk * PSTR + st * 16 + g * 4] = pk;
    }
    const short8 pf0 = *(const short8*)&Ps[q_blk * PSTR + g * 8];
    const short8 pf1 = *(const short8*)&Ps[q_blk * PSTR + g * 8 + 32];

#pragma unroll
    for (int mt = 0; mt < 4; ++mt) {
      const unsigned short* vrow = &Vs[(mt * 16 + lq) * PSTR];
      const short8 vf0 = *(const short8*)&vrow[g * 8];
      const short8 vf1 = *(const short8*)&vrow[g * 8 + 32];
      Ot[mt] = __builtin_amdgcn_mfma_f32_16x16x32_bf16(vf0, pf0, Ot[mt], 0, 0, 0);
      Ot[mt] = __builtin_amdgcn_mfma_f32_16x16x32_bf16(vf1, pf1, Ot[mt], 0, 0, 0);
    }
  }

  const float inv_l = 1.0f / l_run;
  unsigned short* orow = &O[qk_base + (size_t)(qr0 + q_blk) * D_MODEL];
#pragma unroll
  for (int mt = 0; mt < 4; ++mt) {
    uint2 pk;
    pk.x = (unsigned)f2bf(Ot[mt][0] * inv_l) | ((unsigned)f2bf(Ot[mt][1] * inv_l) << 16);
    pk.y = (unsigned)f2bf(Ot[mt][2] * inv_l) | ((unsigned)f2bf(Ot[mt][3] * inv_l) << 16);
    *(uint2*)&orow[mt * 16 + g * 4] = pk;
  }
}

// ---------------------------------------------------------------------------
extern "C" void kernel_launch(void* const* d_in, const int* in_sizes, int n_in,
                              void* d_out, int out_size, void* d_ws, size_t ws_size,
                              hipStream_t stream) {
  const float* x  = (const float*)d_in[0];
  const float* qw = (const float*)d_in[1];
  const float* kw = (const float*)d_in[2];
  const float* vw = (const float*)d_in[3];
  const float* ow = (const float*)d_in[4];
  float* out = (float*)d_out;

  const int M = BATCH * SEQ;               // 4096
  const size_t mat = (size_t)M * D_MODEL;  // 4M elements
  const size_t wmat = (size_t)D_MODEL * D_MODEL;  // 1M elements

  // ws layout (60 MB total, all bf16 ushort):
  unsigned short* qwThi = (unsigned short*)d_ws;   // 2 MB each
  unsigned short* qwTlo = qwThi + wmat;
  unsigned short* kwThi = qwTlo + wmat;
  unsigned short* kwTlo = kwThi + wmat;
  unsigned short* vwT   = kwTlo + wmat;
  unsigned short* owT   = vwT + wmat;
  unsigned short* Qhi   = owT + wmat;              // 8 MB each
  unsigned short* Qlo   = Qhi + mat;
  unsigned short* Khi   = Qlo + mat;
  unsigned short* Klo   = Khi + mat;
  unsigned short* Vt    = Klo + mat;
  unsigned short* At    = Vt + mat;

  dim3 wgrid(32, 32);
  wsplit_kernel<true ><<<wgrid, 256, 0, stream>>>(qw, qwThi, qwTlo);
  wsplit_kernel<true ><<<wgrid, 256, 0, stream>>>(kw, kwThi, kwTlo);
  wsplit_kernel<false><<<wgrid, 256, 0, stream>>>(vw, vwT, nullptr);
  wsplit_kernel<false><<<wgrid, 256, 0, stream>>>(ow, owT, nullptr);

  dim3 ggrid(D_MODEL / 64, M / 64);  // (16, 64) = 1024 blocks, 1 wave each
  gemm64_kernel<1, 1><<<ggrid, 64, 0, stream>>>(x, qwThi, qwTlo, Qhi, Qlo);
  gemm64_kernel<1, 1><<<ggrid, 64, 0, stream>>>(x, kwThi, kwTlo, Khi, Klo);
  gemm64_kernel<0, 2><<<ggrid, 64, 0, stream>>>(x, vwT, nullptr, Vt, nullptr);

  attn_mfma_kernel<<<dim3(SEQ / 64, N_HEADS, BATCH), 256, 0, stream>>>(
      Qhi, Qlo, Khi, Klo, Vt, At);

  gemm64_kernel<2, 0><<<ggrid, 64, 0, stream>>>(At, owT, nullptr, out, nullptr);
}

// Round 5
// 409.819 us; speedup vs baseline: 13.0037x; 1.0555x over previous
//
#include <hip/hip_runtime.h>
#include <hip/hip_bf16.h>
#include <math.h>

#define D_MODEL 1024
#define N_HEADS 16
#define HEAD_DIM 64
#define SEQ 2048
#define BATCH 2

typedef __attribute__((ext_vector_type(8))) short short8;
typedef __attribute__((ext_vector_type(4))) float f32x4;

// scale folded into Q at projection: (1/sqrt(1024)) * log2(e)
#define QSCALE 0.0450842200277948f

__device__ __forceinline__ unsigned short f2bf(float x) {
  union { float f; unsigned u; } v; v.f = x;
  unsigned r = v.u + 0x7FFFu + ((v.u >> 16) & 1u);
  return (unsigned short)(r >> 16);
}
// Truncation hi + RNE lo: pair represents x to ~2^-17 relative.
__device__ __forceinline__ void split2(float x, unsigned short& h, unsigned short& l) {
  union { float f; unsigned u; } v; v.f = x;
  h = (unsigned short)(v.u >> 16);
  l = f2bf(x - __uint_as_float(v.u & 0xFFFF0000u));
}
__device__ __forceinline__ void glds16(const unsigned short* g, unsigned short* l) {
  __builtin_amdgcn_global_load_lds(
      (const __attribute__((address_space(1))) void*)g,
      (__attribute__((address_space(3))) void*)l, 16, 0, 0);
}

// ---------------------------------------------------------------------------
// x fp32 -> Xhi/Xlo bf16 (elementwise, 4 elems/thread)
// ---------------------------------------------------------------------------
__global__ __launch_bounds__(256) void xsplit_kernel(
    const float* __restrict__ X, unsigned short* __restrict__ Xhi,
    unsigned short* __restrict__ Xlo) {
  const size_t i = ((size_t)blockIdx.x * 256 + threadIdx.x) * 4;
  const float4 v = *(const float4*)&X[i];
  unsigned short h0, h1, h2, h3, l0, l1, l2, l3;
  split2(v.x, h0, l0); split2(v.y, h1, l1);
  split2(v.z, h2, l2); split2(v.w, h3, l3);
  uint2 ph, pl;
  ph.x = (unsigned)h0 | ((unsigned)h1 << 16);
  ph.y = (unsigned)h2 | ((unsigned)h3 << 16);
  pl.x = (unsigned)l0 | ((unsigned)l1 << 16);
  pl.y = (unsigned)l2 | ((unsigned)l3 << 16);
  *(uint2*)&Xhi[i] = ph;
  *(uint2*)&Xlo[i] = pl;
}

// ---------------------------------------------------------------------------
// Weight transpose + bf16 split: W fp32 [K][N] -> Thi/Tlo bf16 [N][K].
// ---------------------------------------------------------------------------
template <bool LO>
__global__ __launch_bounds__(256) void wsplit_kernel(
    const float* __restrict__ W, unsigned short* __restrict__ Thi,
    unsigned short* __restrict__ Tlo) {
  __shared__ float t[32][33];
  const int k0 = blockIdx.x * 32, n0 = blockIdx.y * 32;
  const int tx = threadIdx.x & 31, ty = threadIdx.x >> 5;
#pragma unroll
  for (int i = 0; i < 32; i += 8)
    t[ty + i][tx] = W[(size_t)(k0 + ty + i) * D_MODEL + n0 + tx];
  __syncthreads();
#pragma unroll
  for (int i = 0; i < 32; i += 8) {
    unsigned short h, l;
    split2(t[tx][ty + i], h, l);
    const size_t off = (size_t)(n0 + ty + i) * D_MODEL + k0 + tx;
    Thi[off] = h;
    if (LO) Tlo[off] = l;
  }
}

// ---------------------------------------------------------------------------
// Fused Q+K projection GEMM, hi/lo precision (3-MFMA). Single wave, 64x64
// tile, BK=32, double-buffered global_load_lds staging (1 barrier/iter).
// B is stacked [2*D_MODEL][D_MODEL]: rows 0..1023 = qw^T, 1024..2047 = kw^T.
// Q epilogue folds QSCALE before the hi/lo split.
// ---------------------------------------------------------------------------
__global__ __launch_bounds__(64) void gemm_qk_kernel(
    const unsigned short* __restrict__ Xhi, const unsigned short* __restrict__ Xlo,
    const unsigned short* __restrict__ Whi, const unsigned short* __restrict__ Wlo,
    unsigned short* __restrict__ Qhi, unsigned short* __restrict__ Qlo,
    unsigned short* __restrict__ Khi, unsigned short* __restrict__ Klo) {
  __shared__ __align__(16) unsigned short Ah[2][2048], Al[2][2048];
  __shared__ __align__(16) unsigned short Bh[2][2048], Bl[2][2048];
  const int tid = threadIdx.x;
  const int lq = tid & 15, g = tid >> 4;
  const int n0 = blockIdx.x * 64;   // 0..2047 within stacked QK
  const int m0 = blockIdx.y * 64;

  f32x4 acc[4][4];
#pragma unroll
  for (int mi = 0; mi < 4; ++mi)
#pragma unroll
    for (int ni = 0; ni < 4; ++ni) acc[mi][ni] = (f32x4){0.f, 0.f, 0.f, 0.f};

  auto stage = [&](int buf, int k0) {
#pragma unroll
    for (int j = 0; j < 4; ++j) {
      const int e = j * 64 + tid;
      const int r = e >> 2, c8 = (e & 3) * 8;
      glds16(&Xhi[(size_t)(m0 + r) * D_MODEL + k0 + c8], &Ah[buf][e * 8]);
      glds16(&Xlo[(size_t)(m0 + r) * D_MODEL + k0 + c8], &Al[buf][e * 8]);
      glds16(&Whi[(size_t)(n0 + r) * D_MODEL + k0 + c8], &Bh[buf][e * 8]);
      glds16(&Wlo[(size_t)(n0 + r) * D_MODEL + k0 + c8], &Bl[buf][e * 8]);
    }
  };

  stage(0, 0);
  int buf = 0;
  for (int k0 = 0; k0 < D_MODEL; k0 += 32) {
    __syncthreads();  // drains vmcnt: current buf ready; prior reads done
    if (k0 + 32 < D_MODEL) stage(buf ^ 1, k0 + 32);
    short8 ah[4], al[4], bh[4], bl[4];
#pragma unroll
    for (int i = 0; i < 4; ++i) {
      ah[i] = *(const short8*)&Ah[buf][(i * 16 + lq) * 32 + g * 8];
      al[i] = *(const short8*)&Al[buf][(i * 16 + lq) * 32 + g * 8];
      bh[i] = *(const short8*)&Bh[buf][(i * 16 + lq) * 32 + g * 8];
      bl[i] = *(const short8*)&Bl[buf][(i * 16 + lq) * 32 + g * 8];
    }
#pragma unroll
    for (int mi = 0; mi < 4; ++mi)
#pragma unroll
      for (int ni = 0; ni < 4; ++ni) {
        acc[mi][ni] = __builtin_amdgcn_mfma_f32_16x16x32_bf16(ah[mi], bh[ni], acc[mi][ni], 0, 0, 0);
        acc[mi][ni] = __builtin_amdgcn_mfma_f32_16x16x32_bf16(ah[mi], bl[ni], acc[mi][ni], 0, 0, 0);
        acc[mi][ni] = __builtin_amdgcn_mfma_f32_16x16x32_bf16(al[mi], bh[ni], acc[mi][ni], 0, 0, 0);
      }
    buf ^= 1;
  }

  const bool isQ = (n0 < D_MODEL);
  unsigned short* Dhi = isQ ? Qhi : Khi;
  unsigned short* Dlo = isQ ? Qlo : Klo;
  const float sc = isQ ? QSCALE : 1.0f;
  const int nbase = n0 & (D_MODEL - 1);
#pragma unroll
  for (int mi = 0; mi < 4; ++mi)
#pragma unroll
    for (int ni = 0; ni < 4; ++ni) {
      const int gm = m0 + mi * 16 + g * 4;
      const int gn = nbase + ni * 16 + lq;
#pragma unroll
      for (int r = 0; r < 4; ++r) {
        unsigned short h, l;
        split2(acc[mi][ni][r] * sc, h, l);
        Dhi[(size_t)(gm + r) * D_MODEL + gn] = h;
        Dlo[(size_t)(gm + r) * D_MODEL + gn] = l;
      }
    }
}

// ---------------------------------------------------------------------------
// Plain bf16 GEMM (single wave, 64x64, BK=32, dbuf glds).
// CM 0: fp32 C row-major. CM 2: bf16 C transposed into Vt[b][h][dh][s].
// ---------------------------------------------------------------------------
template <int CM>
__global__ __launch_bounds__(64) void gemm_plain_kernel(
    const unsigned short* __restrict__ A, const unsigned short* __restrict__ B,
    void* __restrict__ C) {
  __shared__ __align__(16) unsigned short Ah[2][2048], Bh[2][2048];
  const int tid = threadIdx.x;
  const int lq = tid & 15, g = tid >> 4;
  const int n0 = blockIdx.x * 64;
  const int m0 = blockIdx.y * 64;

  f32x4 acc[4][4];
#pragma unroll
  for (int mi = 0; mi < 4; ++mi)
#pragma unroll
    for (int ni = 0; ni < 4; ++ni) acc[mi][ni] = (f32x4){0.f, 0.f, 0.f, 0.f};

  auto stage = [&](int buf, int k0) {
#pragma unroll
    for (int j = 0; j < 4; ++j) {
      const int e = j * 64 + tid;
      const int r = e >> 2, c8 = (e & 3) * 8;
      glds16(&A[(size_t)(m0 + r) * D_MODEL + k0 + c8], &Ah[buf][e * 8]);
      glds16(&B[(size_t)(n0 + r) * D_MODEL + k0 + c8], &Bh[buf][e * 8]);
    }
  };

  stage(0, 0);
  int buf = 0;
  for (int k0 = 0; k0 < D_MODEL; k0 += 32) {
    __syncthreads();
    if (k0 + 32 < D_MODEL) stage(buf ^ 1, k0 + 32);
    short8 ah[4], bh[4];
#pragma unroll
    for (int i = 0; i < 4; ++i) {
      ah[i] = *(const short8*)&Ah[buf][(i * 16 + lq) * 32 + g * 8];
      bh[i] = *(const short8*)&Bh[buf][(i * 16 + lq) * 32 + g * 8];
    }
#pragma unroll
    for (int mi = 0; mi < 4; ++mi)
#pragma unroll
      for (int ni = 0; ni < 4; ++ni)
        acc[mi][ni] = __builtin_amdgcn_mfma_f32_16x16x32_bf16(ah[mi], bh[ni], acc[mi][ni], 0, 0, 0);
    buf ^= 1;
  }

#pragma unroll
  for (int mi = 0; mi < 4; ++mi)
#pragma unroll
    for (int ni = 0; ni < 4; ++ni) {
      const int gm = m0 + mi * 16 + g * 4;
      const int gn = n0 + ni * 16 + lq;
      if constexpr (CM == 0) {
        float* Cf = (float*)C;
#pragma unroll
        for (int r = 0; r < 4; ++r)
          Cf[(size_t)(gm + r) * D_MODEL + gn] = acc[mi][ni][r];
      } else {  // Vt[b][h][dh][s]; rows gm..gm+3 are 4 consecutive s
        const int bb = gm >> 11, s = gm & 2047;
        const int hh = gn >> 6, dh = gn & 63;
        uint2 pk;
        pk.x = (unsigned)f2bf(acc[mi][ni][0]) | ((unsigned)f2bf(acc[mi][ni][1]) << 16);
        pk.y = (unsigned)f2bf(acc[mi][ni][2]) | ((unsigned)f2bf(acc[mi][ni][3]) << 16);
        unsigned short* Vt = (unsigned short*)C;
        *(uint2*)&Vt[(((size_t)bb * N_HEADS + hh) * HEAD_DIM + dh) * SEQ + s] = pk;
      }
    }
}

// ---------------------------------------------------------------------------
// MFMA flash attention v2 (causal): QT=128 (2 q-subtiles/wave), KT=64,
// register-prefetched K/V staging, exp2-domain online softmax (scale*log2e
// pre-folded into Q). Scores via hi/lo 3-term MFMA.
// grid (SEQ/128, N_HEADS, BATCH) with qti reversed (heavy blocks first).
// ---------------------------------------------------------------------------
#define PSTR 72  // LDS row stride in bf16 (64 data + 8 pad)

__device__ __forceinline__ void softmax_pv(
    const f32x4 S[4], bool diag, int kr0, int qr0, int q_local, int g,
    float& m_run, float& l_run, f32x4 Ot[4], unsigned short* PsRow,
    const short8 vf0[4], const short8 vf1[4]) {
  float sv[16];
  float tmax = -3.0e38f;
#pragma unroll
  for (int st = 0; st < 4; ++st)
#pragma unroll
    for (int r = 0; r < 4; ++r) {
      float s = S[st][r];
      if (diag && (kr0 + st * 16 + g * 4 + r) > (qr0 + q_local)) s = -1.0e30f;
      sv[st * 4 + r] = s;
      tmax = fmaxf(tmax, s);
    }
  tmax = fmaxf(tmax, __shfl_xor(tmax, 16));
  tmax = fmaxf(tmax, __shfl_xor(tmax, 32));
  const float m_new = fmaxf(m_run, tmax);
  const float alpha = exp2f(m_run - m_new);  // first iter: exp2(-inf)=0
  m_run = m_new;
  float psum = 0.f;
#pragma unroll
  for (int i = 0; i < 16; ++i) {
    sv[i] = exp2f(sv[i] - m_new);
    psum += sv[i];
  }
  psum += __shfl_xor(psum, 16);
  psum += __shfl_xor(psum, 32);
  l_run = l_run * alpha + psum;
#pragma unroll
  for (int mt = 0; mt < 4; ++mt) {
    Ot[mt][0] *= alpha; Ot[mt][1] *= alpha;
    Ot[mt][2] *= alpha; Ot[mt][3] *= alpha;
  }
  // P^T (C-layout) -> P[q][k] in LDS; wave-private row, then read A-frag
#pragma unroll
  for (int st = 0; st < 4; ++st) {
    uint2 pk;
    pk.x = (unsigned)f2bf(sv[st * 4 + 0]) | ((unsigned)f2bf(sv[st * 4 + 1]) << 16);
    pk.y = (unsigned)f2bf(sv[st * 4 + 2]) | ((unsigned)f2bf(sv[st * 4 + 3]) << 16);
    *(uint2*)&PsRow[st * 16 + g * 4] = pk;
  }
  const short8 pf0 = *(const short8*)&PsRow[g * 8];
  const short8 pf1 = *(const short8*)&PsRow[g * 8 + 32];
#pragma unroll
  for (int mt = 0; mt < 4; ++mt) {
    Ot[mt] = __builtin_amdgcn_mfma_f32_16x16x32_bf16(vf0[mt], pf0, Ot[mt], 0, 0, 0);
    Ot[mt] = __builtin_amdgcn_mfma_f32_16x16x32_bf16(vf1[mt], pf1, Ot[mt], 0, 0, 0);
  }
}

__global__ __launch_bounds__(256) void attn_mfma2_kernel(
    const unsigned short* __restrict__ Qhi, const unsigned short* __restrict__ Qlo,
    const unsigned short* __restrict__ Khi, const unsigned short* __restrict__ Klo,
    const unsigned short* __restrict__ Vt,  // bf16 [B][H][HEAD_DIM][S]
    unsigned short* __restrict__ O) {       // bf16 [B*S][D_MODEL] head-merged
  __shared__ __align__(16) unsigned short Khs[64 * PSTR];
  __shared__ __align__(16) unsigned short Kls[64 * PSTR];
  __shared__ __align__(16) unsigned short Vs[64 * PSTR];
  __shared__ __align__(16) unsigned short Ps[128 * PSTR];

  const int tid = threadIdx.x;
  const int lane = tid & 63;
  const int w = tid >> 6;
  const int lq = lane & 15;
  const int g = lane >> 4;
  const int qti = (int)gridDim.x - 1 - (int)blockIdx.x;  // heavy-first
  const int h = blockIdx.y;
  const int b = blockIdx.z;
  const int qr0 = qti * 128;

  const size_t base = ((size_t)b * SEQ) * D_MODEL + (size_t)h * HEAD_DIM;
  const unsigned short* Vtb = Vt + ((size_t)(b * N_HEADS + h) * HEAD_DIM) * SEQ;

  const int qA = w * 16 + lq;
  const int qB = qA + 64;
  const size_t qoffA = base + (size_t)(qr0 + qA) * D_MODEL;
  const size_t qoffB = base + (size_t)(qr0 + qB) * D_MODEL;
  const short8 qh0A = *(const short8*)&Qhi[qoffA + g * 8];
  const short8 qh1A = *(const short8*)&Qhi[qoffA + g * 8 + 32];
  const short8 ql0A = *(const short8*)&Qlo[qoffA + g * 8];
  const short8 ql1A = *(const short8*)&Qlo[qoffA + g * 8 + 32];
  const short8 qh0B = *(const short8*)&Qhi[qoffB + g * 8];
  const short8 qh1B = *(const short8*)&Qhi[qoffB + g * 8 + 32];
  const short8 ql0B = *(const short8*)&Qlo[qoffB + g * 8];
  const short8 ql1B = *(const short8*)&Qlo[qoffB + g * 8 + 32];

  f32x4 OtA[4], OtB[4];
#pragma unroll
  for (int mt = 0; mt < 4; ++mt) {
    OtA[mt] = (f32x4){0.f, 0.f, 0.f, 0.f};
    OtB[mt] = (f32x4){0.f, 0.f, 0.f, 0.f};
  }
  float mA = -INFINITY, lA = 0.f, mB = -INFINITY, lB = 0.f;

  const int ktmax = 2 * qti + 1;
  uint4 rK[2], rL[2], rV[2];
  auto loadt = [&](int kt) {
    const int kr0 = kt * 64;
#pragma unroll
    for (int it = 0; it < 2; ++it) {
      const int id = it * 256 + tid;
      const int r = id >> 3, c8 = (id & 7) * 8;
      const size_t koff = base + (size_t)(kr0 + r) * D_MODEL + c8;
      rK[it] = *(const uint4*)&Khi[koff];
      rL[it] = *(const uint4*)&Klo[koff];
      rV[it] = *(const uint4*)&Vtb[(size_t)r * SEQ + kr0 + c8];
    }
  };

  loadt(0);
  for (int kt = 0; kt <= ktmax; ++kt) {
    const int kr0 = kt * 64;
    __syncthreads();  // all waves done reading previous tile
#pragma unroll
    for (int it = 0; it < 2; ++it) {
      const int id = it * 256 + tid;
      const int r = id >> 3, c8 = (id & 7) * 8;
      *(uint4*)&Khs[r * PSTR + c8] = rK[it];
      *(uint4*)&Kls[r * PSTR + c8] = rL[it];
      *(uint4*)&Vs[r * PSTR + c8]  = rV[it];
    }
    __syncthreads();  // tile visible
    if (kt < ktmax) loadt(kt + 1);  // in flight during compute

    const bool doA = (kr0 <= qr0 + 63);
    f32x4 SA[4], SB[4];
#pragma unroll
    for (int st = 0; st < 4; ++st) {
      const unsigned short* khr = &Khs[(st * 16 + lq) * PSTR];
      const unsigned short* klr = &Kls[(st * 16 + lq) * PSTR];
      const short8 kh0 = *(const short8*)&khr[g * 8];
      const short8 kh1 = *(const short8*)&khr[g * 8 + 32];
      const short8 kl0 = *(const short8*)&klr[g * 8];
      const short8 kl1 = *(const short8*)&klr[g * 8 + 32];
      if (doA) {
        f32x4 s = (f32x4){0.f, 0.f, 0.f, 0.f};
        s = __builtin_amdgcn_mfma_f32_16x16x32_bf16(kh0, qh0A, s, 0, 0, 0);
        s = __builtin_amdgcn_mfma_f32_16x16x32_bf16(kh1, qh1A, s, 0, 0, 0);
        s = __builtin_amdgcn_mfma_f32_16x16x32_bf16(kh0, ql0A, s, 0, 0, 0);
        s = __builtin_amdgcn_mfma_f32_16x16x32_bf16(kh1, ql1A, s, 0, 0, 0);
        s = __builtin_amdgcn_mfma_f32_16x16x32_bf16(kl0, qh0A, s, 0, 0, 0);
        s = __builtin_amdgcn_mfma_f32_16x16x32_bf16(kl1, qh1A, s, 0, 0, 0);
        SA[st] = s;
      }
      {
        f32x4 s = (f32x4){0.f, 0.f, 0.f, 0.f};
        s = __builtin_amdgcn_mfma_f32_16x16x32_bf16(kh0, qh0B, s, 0, 0, 0);
        s = __builtin_amdgcn_mfma_f32_16x16x32_bf16(kh1, qh1B, s, 0, 0, 0);
        s = __builtin_amdgcn_mfma_f32_16x16x32_bf16(kh0, ql0B, s, 0, 0, 0);
        s = __builtin_amdgcn_mfma_f32_16x16x32_bf16(kh1, ql1B, s, 0, 0, 0);
        s = __builtin_amdgcn_mfma_f32_16x16x32_bf16(kl0, qh0B, s, 0, 0, 0);
        s = __builtin_amdgcn_mfma_f32_16x16x32_bf16(kl1, qh1B, s, 0, 0, 0);
        SB[st] = s;
      }
    }
    short8 vf0[4], vf1[4];
#pragma unroll
    for (int mt = 0; mt < 4; ++mt) {
      vf0[mt] = *(const short8*)&Vs[(mt * 16 + lq) * PSTR + g * 8];
      vf1[mt] = *(const short8*)&Vs[(mt * 16 + lq) * PSTR + g * 8 + 32];
    }
    if (doA)
      softmax_pv(SA, kt == 2 * qti, kr0, qr0, qA, g, mA, lA, OtA,
                 &Ps[(size_t)qA * PSTR], vf0, vf1);
    softmax_pv(SB, kt == 2 * qti + 1, kr0, qr0, qB, g, mB, lB, OtB,
               &Ps[(size_t)qB * PSTR], vf0, vf1);
  }

  const float invA = 1.0f / lA, invB = 1.0f / lB;
  unsigned short* rowA = &O[qoffA];
  unsigned short* rowB = &O[qoffB];
#pragma unroll
  for (int mt = 0; mt < 4; ++mt) {
    uint2 pa, pb;
    pa.x = (unsigned)f2bf(OtA[mt][0] * invA) | ((unsigned)f2bf(OtA[mt][1] * invA) << 16);
    pa.y = (unsigned)f2bf(OtA[mt][2] * invA) | ((unsigned)f2bf(OtA[mt][3] * invA) << 16);
    pb.x = (unsigned)f2bf(OtB[mt][0] * invB) | ((unsigned)f2bf(OtB[mt][1] * invB) << 16);
    pb.y = (unsigned)f2bf(OtB[mt][2] * invB) | ((unsigned)f2bf(OtB[mt][3] * invB) << 16);
    *(uint2*)&rowA[mt * 16 + g * 4] = pa;
    *(uint2*)&rowB[mt * 16 + g * 4] = pb;
  }
}

// ---------------------------------------------------------------------------
extern "C" void kernel_launch(void* const* d_in, const int* in_sizes, int n_in,
                              void* d_out, int out_size, void* d_ws, size_t ws_size,
                              hipStream_t stream) {
  const float* x  = (const float*)d_in[0];
  const float* qw = (const float*)d_in[1];
  const float* kw = (const float*)d_in[2];
  const float* vw = (const float*)d_in[3];
  const float* ow = (const float*)d_in[4];
  float* out = (float*)d_out;

  const int M = BATCH * SEQ;                       // 4096
  const size_t mat  = (size_t)M * D_MODEL;         // 4M elems
  const size_t wmat = (size_t)D_MODEL * D_MODEL;   // 1M elems

  // ws (ushort units), 58.7 MB total, time-multiplexed:
  unsigned short* ws  = (unsigned short*)d_ws;
  unsigned short* Xhi = ws;                   // [mat]   later: At
  unsigned short* Xlo = Xhi + mat;            // [mat]   later: Vt
  unsigned short* Whi = Xlo + mat;            // [2*wmat] stacked qk hi; later owT
  unsigned short* Wlo = Whi + 2 * wmat;       // [2*wmat] stacked qk lo; later vwT
  unsigned short* Qhi = Wlo + 2 * wmat;       // [mat]
  unsigned short* Qlo = Qhi + mat;
  unsigned short* Khi = Qlo + mat;
  unsigned short* Klo = Khi + mat;
  unsigned short* At  = Xhi;   // alias (Xhi dead after V-GEMM)
  unsigned short* Vt  = Xlo;   // alias (Xlo dead after QK-GEMM)
  unsigned short* owT = Whi;   // alias (Whi dead after QK-GEMM)
  unsigned short* vwT = Wlo;   // alias (Wlo dead after QK-GEMM)

  dim3 wgrid(32, 32);
  xsplit_kernel<<<dim3(mat / 1024), 256, 0, stream>>>(x, Xhi, Xlo);
  wsplit_kernel<true><<<wgrid, 256, 0, stream>>>(qw, Whi, Wlo);
  wsplit_kernel<true><<<wgrid, 256, 0, stream>>>(kw, Whi + wmat, Wlo + wmat);

  gemm_qk_kernel<<<dim3(32, 64), 64, 0, stream>>>(Xhi, Xlo, Whi, Wlo,
                                                  Qhi, Qlo, Khi, Klo);

  wsplit_kernel<false><<<wgrid, 256, 0, stream>>>(vw, vwT, nullptr);
  wsplit_kernel<false><<<wgrid, 256, 0, stream>>>(ow, owT, nullptr);

  gemm_plain_kernel<2><<<dim3(16, 64), 64, 0, stream>>>(Xhi, vwT, Vt);

  attn_mfma2_kernel<<<dim3(SEQ / 128, N_HEADS, BATCH), 256, 0, stream>>>(
      Qhi, Qlo, Khi, Klo, Vt, At);

  gemm_plain_kernel<0><<<dim3(16, 64), 64, 0, stream>>>(At, owT, out);
}